// Round 1
// baseline (659.780 us; speedup 1.0000x reference)
//
#include <hip/hip_runtime.h>
#include <hip/hip_bf16.h>

// Problem constants (fixed by reference)
#define IN_F   4096
#define OUT_F  4096
#define RANK   16
#define M_TOK  8192          // 4 * 2048 tokens
#define SCALING 2.0f         // ALPHA / RANK = 32/16

typedef __attribute__((ext_vector_type(8))) short short8;   // 8 bf16 = 4 VGPRs
typedef __attribute__((ext_vector_type(4))) float f32x4;

// ---------------------------------------------------------------------------
// Kernel 1: x fp32 -> bf16 (vectorized 8 elems/thread)
// ---------------------------------------------------------------------------
__global__ __launch_bounds__(256) void cvt_x_bf16(const float* __restrict__ x,
                                                  __hip_bfloat16* __restrict__ y) {
    size_t i = ((size_t)blockIdx.x * 256 + threadIdx.x) * 8;
    float4 a = *(const float4*)(x + i);
    float4 b = *(const float4*)(x + i + 4);
    union { uint4 u; __hip_bfloat16 h[8]; } p;
    p.h[0] = __float2bfloat16(a.x);
    p.h[1] = __float2bfloat16(a.y);
    p.h[2] = __float2bfloat16(a.z);
    p.h[3] = __float2bfloat16(a.w);
    p.h[4] = __float2bfloat16(b.x);
    p.h[5] = __float2bfloat16(b.y);
    p.h[6] = __float2bfloat16(b.z);
    p.h[7] = __float2bfloat16(b.w);
    *(uint4*)(y + i) = p.u;
}

// ---------------------------------------------------------------------------
// Kernel 2: dequant int4 codes + fold LoRA:  W'[o,i] = (q-8)*scale + 2*(B@A)[o,i]
// block = 256 threads, 4 elems/thread => 1024 cols/block; grid = (I/1024, O)
// ---------------------------------------------------------------------------
__global__ __launch_bounds__(256) void dequant_fold(const int* __restrict__ q,
                                                    const float* __restrict__ sc,
                                                    const float* __restrict__ lA,
                                                    const float* __restrict__ lB,
                                                    __hip_bfloat16* __restrict__ W) {
    const int o  = blockIdx.y;
    const int i0 = blockIdx.x * 1024 + threadIdx.x * 4;

    float b[RANK];
#pragma unroll
    for (int r = 0; r < RANK; ++r) b[r] = lB[o * RANK + r];   // uniform -> SGPR

    int4  qv = *(const int4*)(q + (size_t)o * IN_F + i0);
    float s  = sc[o * (IN_F / 64) + (i0 >> 6)];               // same 64-block for 4 elems

    float l0 = 0.f, l1 = 0.f, l2 = 0.f, l3 = 0.f;
#pragma unroll
    for (int r = 0; r < RANK; ++r) {
        float4 av = *(const float4*)(lA + (size_t)r * IN_F + i0);
        l0 += b[r] * av.x; l1 += b[r] * av.y;
        l2 += b[r] * av.z; l3 += b[r] * av.w;
    }
    union { ushort4 u; __hip_bfloat16 h[4]; } p;
    p.h[0] = __float2bfloat16((float)(qv.x - 8) * s + SCALING * l0);
    p.h[1] = __float2bfloat16((float)(qv.y - 8) * s + SCALING * l1);
    p.h[2] = __float2bfloat16((float)(qv.z - 8) * s + SCALING * l2);
    p.h[3] = __float2bfloat16((float)(qv.w - 8) * s + SCALING * l3);
    *(ushort4*)(W + (size_t)o * IN_F + i0) = p.u;
}

// ---------------------------------------------------------------------------
// Kernel 3: C[M,N] = A[M,K] * B[N,K]^T + bias   (m97-pattern 128x128 tile)
// 256 threads = 4 waves, each wave does a 64x64 quadrant via 4x4 MFMA 16x16x32.
// global_load_lds width=16 staging; LDS layout is exactly wave-uniform base +
// lane*16 (thread t -> row t/4, 8-elem chunk t%4) so no padding.
// ---------------------------------------------------------------------------
#define BM 128
#define BN 128
#define BK 32

__device__ __forceinline__ void load_lds16(const void* g, void* l) {
    __builtin_amdgcn_global_load_lds(
        (const __attribute__((address_space(1))) unsigned int*)g,
        (__attribute__((address_space(3))) unsigned int*)l, 16, 0, 0);
}

__global__ __launch_bounds__(256) void gemm_bt_bias(const __hip_bfloat16* __restrict__ A,
                                                    const __hip_bfloat16* __restrict__ B,
                                                    const float* __restrict__ bias,
                                                    float* __restrict__ C) {
    __shared__ __hip_bfloat16 a_sh[BM * BK];   // 8 KB, row-major [128][32], no pad
    __shared__ __hip_bfloat16 b_sh[BN * BK];   // 8 KB

    const int tid  = threadIdx.x;
    const int lane = tid & 63;
    const int wave = tid >> 6;
    const int bm = blockIdx.y * BM;
    const int bn = blockIdx.x * BN;
    const int wm = (wave >> 1) * 64;           // 2x2 wave grid over 128x128
    const int wn = (wave & 1) * 64;

    // staging: thread t loads 16B at (row = t/4, elem chunk = (t%4)*8)
    const int srow = tid >> 2;
    const int scol = (tid & 3) * 8;
    const __hip_bfloat16* ap0 = A + (size_t)(bm + srow) * IN_F + scol;
    const __hip_bfloat16* ap1 = ap0 + (size_t)64 * IN_F;
    const __hip_bfloat16* bp0 = B + (size_t)(bn + srow) * IN_F + scol;
    const __hip_bfloat16* bp1 = bp0 + (size_t)64 * IN_F;

    // wave-uniform LDS dest bases (wave w stages rows 16w..16w+15 => elem w*512)
    __hip_bfloat16* a_d0 = a_sh + wave * 512;
    __hip_bfloat16* a_d1 = a_sh + 2048 + wave * 512;
    __hip_bfloat16* b_d0 = b_sh + wave * 512;
    __hip_bfloat16* b_d1 = b_sh + 2048 + wave * 512;

    f32x4 acc[4][4] = {};

    const short* a_s = (const short*)a_sh;
    const short* b_s = (const short*)b_sh;
    // fragment read offsets: A lane layout m = lane&15, k-chunk = (lane>>4)*8
    const int a_off = (wm + (lane & 15)) * BK + (lane >> 4) * 8;
    const int b_off = (wn + (lane & 15)) * BK + (lane >> 4) * 8;

    for (int k0 = 0; k0 < IN_F; k0 += BK) {
        __syncthreads();                       // prev tile fully consumed
        load_lds16(ap0, a_d0);
        load_lds16(ap1, a_d1);
        load_lds16(bp0, b_d0);
        load_lds16(bp1, b_d1);
        ap0 += BK; ap1 += BK; bp0 += BK; bp1 += BK;
        __syncthreads();                       // staging drained (vmcnt(0))

        short8 af[4], bf[4];
#pragma unroll
        for (int i = 0; i < 4; ++i)
            af[i] = *(const short8*)(a_s + a_off + i * 16 * BK);   // ds_read_b128
#pragma unroll
        for (int j = 0; j < 4; ++j)
            bf[j] = *(const short8*)(b_s + b_off + j * 16 * BK);
#pragma unroll
        for (int i = 0; i < 4; ++i)
#pragma unroll
            for (int j = 0; j < 4; ++j)
                acc[i][j] = __builtin_amdgcn_mfma_f32_16x16x32_bf16(af[i], bf[j],
                                                                    acc[i][j], 0, 0, 0);
    }

    // epilogue: D[row=(lane>>4)*4+r][col=lane&15] per 16x16 tile; fuse bias
    const int qd = lane >> 4;
    const int cl = lane & 15;
#pragma unroll
    for (int j = 0; j < 4; ++j) {
        const int n = bn + wn + j * 16 + cl;
        const float bv = bias[n];
#pragma unroll
        for (int i = 0; i < 4; ++i) {
            const int m0 = bm + wm + i * 16 + qd * 4;
#pragma unroll
            for (int r = 0; r < 4; ++r)
                C[(size_t)(m0 + r) * OUT_F + n] = acc[i][j][r] + bv;
        }
    }
}

// ---------------------------------------------------------------------------
extern "C" void kernel_launch(void* const* d_in, const int* in_sizes, int n_in,
                              void* d_out, int out_size, void* d_ws, size_t ws_size,
                              hipStream_t stream) {
    const float* x    = (const float*)d_in[0];   // [4,2048,4096] fp32
    const int*   qc   = (const int*)d_in[1];     // [4096,4096] int32 codes
    const float* sc   = (const float*)d_in[2];   // [4096,64] fp32
    const float* bias = (const float*)d_in[3];   // [4096]
    const float* lA   = (const float*)d_in[4];   // [16,4096]
    const float* lB   = (const float*)d_in[5];   // [4096,16]
    float* out = (float*)d_out;                  // [4,2048,4096] fp32

    // workspace: x_bf16 (64 MB) + W'_bf16 (32 MB) = 96 MB
    __hip_bfloat16* xb = (__hip_bfloat16*)d_ws;
    __hip_bfloat16* wb = xb + (size_t)M_TOK * IN_F;

    cvt_x_bf16<<<(M_TOK * IN_F) / (256 * 8), 256, 0, stream>>>(x, xb);
    dequant_fold<<<dim3(IN_F / 1024, OUT_F), 256, 0, stream>>>(qc, sc, lA, lB, wb);
    gemm_bt_bias<<<dim3(OUT_F / BN, M_TOK / BM), 256, 0, stream>>>(xb, wb, bias, out);
}

// Round 3
// 643.602 us; speedup vs baseline: 1.0251x; 1.0251x over previous
//
#include <hip/hip_runtime.h>
#include <hip/hip_bf16.h>

// Problem constants (fixed by reference)
#define IN_F   4096
#define OUT_F  4096
#define RANK   16
#define M_TOK  8192          // 4 * 2048 tokens
#define SCALING 2.0f         // ALPHA / RANK = 32/16

typedef __attribute__((ext_vector_type(8))) short short8;   // 8 bf16 = 4 VGPRs
typedef __attribute__((ext_vector_type(4))) float f32x4;
typedef __attribute__((ext_vector_type(4))) float fvec4;    // clang vec: ok for nontemporal
typedef __attribute__((ext_vector_type(4))) int   ivec4;
typedef __attribute__((ext_vector_type(4))) unsigned int uvec4;

// ---------------------------------------------------------------------------
// Fused prep kernel. Even blocks: x fp32->bf16 (8 elems/thread).
// Odd blocks: dequant int4 + fold LoRA: W'[o,i] = (q-8)*scale + 2*(B@A)[o,i].
// Interleaved so both memory streams overlap; stream-once inputs (x, q) use
// nontemporal loads to avoid evicting reused data (lA, and gemm's A/B) from L3.
// ---------------------------------------------------------------------------
__global__ __launch_bounds__(256) void prep_fused(const float* __restrict__ x,
                                                  __hip_bfloat16* __restrict__ xb,
                                                  const int* __restrict__ q,
                                                  const float* __restrict__ sc,
                                                  const float* __restrict__ lA,
                                                  const float* __restrict__ lB,
                                                  __hip_bfloat16* __restrict__ W) {
    const int bid = blockIdx.x;
    if ((bid & 1) == 0) {
        // ---- cvt: x fp32 -> bf16 ----
        size_t i = ((size_t)(bid >> 1) * 256 + threadIdx.x) * 8;
        fvec4 a = __builtin_nontemporal_load((const fvec4*)(x + i));
        fvec4 b = __builtin_nontemporal_load((const fvec4*)(x + i + 4));
        union { uvec4 u; __hip_bfloat16 h[8]; } p;
        p.h[0] = __float2bfloat16(a.x);
        p.h[1] = __float2bfloat16(a.y);
        p.h[2] = __float2bfloat16(a.z);
        p.h[3] = __float2bfloat16(a.w);
        p.h[4] = __float2bfloat16(b.x);
        p.h[5] = __float2bfloat16(b.y);
        p.h[6] = __float2bfloat16(b.z);
        p.h[7] = __float2bfloat16(b.w);
        *(uvec4*)(xb + i) = p.u;
    } else {
        // ---- dequant + LoRA fold: 1024 cols/block, 4 elems/thread ----
        const int db = bid >> 1;
        const int o  = db >> 2;
        const int i0 = (db & 3) * 1024 + threadIdx.x * 4;

        float b[RANK];
#pragma unroll
        for (int r = 0; r < RANK; ++r) b[r] = lB[o * RANK + r];   // uniform -> SGPR

        ivec4 qv = __builtin_nontemporal_load((const ivec4*)(q + (size_t)o * IN_F + i0));
        float s  = sc[o * (IN_F / 64) + (i0 >> 6)];               // same 64-block for 4 elems

        float l0 = 0.f, l1 = 0.f, l2 = 0.f, l3 = 0.f;
#pragma unroll
        for (int r = 0; r < RANK; ++r) {
            fvec4 av = *(const fvec4*)(lA + (size_t)r * IN_F + i0);  // reused: keep cached
            l0 += b[r] * av.x; l1 += b[r] * av.y;
            l2 += b[r] * av.z; l3 += b[r] * av.w;
        }
        union { ushort4 u; __hip_bfloat16 h[4]; } p;
        p.h[0] = __float2bfloat16((float)(qv.x - 8) * s + SCALING * l0);
        p.h[1] = __float2bfloat16((float)(qv.y - 8) * s + SCALING * l1);
        p.h[2] = __float2bfloat16((float)(qv.z - 8) * s + SCALING * l2);
        p.h[3] = __float2bfloat16((float)(qv.w - 8) * s + SCALING * l3);
        *(ushort4*)(W + (size_t)o * IN_F + i0) = p.u;
    }
}

// ---------------------------------------------------------------------------
// GEMM: C[M,N] = A[M,K] * B[N,K]^T + bias   (m97-pattern 128x128 tile)
// 256 threads = 4 waves, each wave does a 64x64 quadrant via 4x4 MFMA 16x16x32.
// global_load_lds width=16 staging; C stored with nontemporal stores so the
// 128 MB output stream does not evict the (96 MB, fully-L3-resident) A+B.
// ---------------------------------------------------------------------------
#define BM 128
#define BN 128
#define BK 32

__device__ __forceinline__ void load_lds16(const void* g, void* l) {
    __builtin_amdgcn_global_load_lds(
        (const __attribute__((address_space(1))) unsigned int*)g,
        (__attribute__((address_space(3))) unsigned int*)l, 16, 0, 0);
}

__global__ __launch_bounds__(256) void gemm_bt_bias(const __hip_bfloat16* __restrict__ A,
                                                    const __hip_bfloat16* __restrict__ B,
                                                    const float* __restrict__ bias,
                                                    float* __restrict__ C) {
    __shared__ __hip_bfloat16 a_sh[BM * BK];   // 8 KB, row-major [128][32], no pad
    __shared__ __hip_bfloat16 b_sh[BN * BK];   // 8 KB

    const int tid  = threadIdx.x;
    const int lane = tid & 63;
    const int wave = tid >> 6;
    const int bm = blockIdx.y * BM;
    const int bn = blockIdx.x * BN;
    const int wm = (wave >> 1) * 64;           // 2x2 wave grid over 128x128
    const int wn = (wave & 1) * 64;

    // staging: thread t loads 16B at (row = t/4, elem chunk = (t%4)*8)
    const int srow = tid >> 2;
    const int scol = (tid & 3) * 8;
    const __hip_bfloat16* ap0 = A + (size_t)(bm + srow) * IN_F + scol;
    const __hip_bfloat16* ap1 = ap0 + (size_t)64 * IN_F;
    const __hip_bfloat16* bp0 = B + (size_t)(bn + srow) * IN_F + scol;
    const __hip_bfloat16* bp1 = bp0 + (size_t)64 * IN_F;

    // wave-uniform LDS dest bases (wave w stages rows 16w..16w+15 => elem w*512)
    __hip_bfloat16* a_d0 = a_sh + wave * 512;
    __hip_bfloat16* a_d1 = a_sh + 2048 + wave * 512;
    __hip_bfloat16* b_d0 = b_sh + wave * 512;
    __hip_bfloat16* b_d1 = b_sh + 2048 + wave * 512;

    f32x4 acc[4][4] = {};

    const short* a_s = (const short*)a_sh;
    const short* b_s = (const short*)b_sh;
    // fragment read offsets: A lane layout m = lane&15, k-chunk = (lane>>4)*8
    const int a_off = (wm + (lane & 15)) * BK + (lane >> 4) * 8;
    const int b_off = (wn + (lane & 15)) * BK + (lane >> 4) * 8;

    for (int k0 = 0; k0 < IN_F; k0 += BK) {
        __syncthreads();                       // prev tile fully consumed
        load_lds16(ap0, a_d0);
        load_lds16(ap1, a_d1);
        load_lds16(bp0, b_d0);
        load_lds16(bp1, b_d1);
        ap0 += BK; ap1 += BK; bp0 += BK; bp1 += BK;
        __syncthreads();                       // staging drained (vmcnt(0))

        short8 af[4], bf[4];
#pragma unroll
        for (int i = 0; i < 4; ++i)
            af[i] = *(const short8*)(a_s + a_off + i * 16 * BK);   // ds_read_b128
#pragma unroll
        for (int j = 0; j < 4; ++j)
            bf[j] = *(const short8*)(b_s + b_off + j * 16 * BK);
#pragma unroll
        for (int i = 0; i < 4; ++i)
#pragma unroll
            for (int j = 0; j < 4; ++j)
                acc[i][j] = __builtin_amdgcn_mfma_f32_16x16x32_bf16(af[i], bf[j],
                                                                    acc[i][j], 0, 0, 0);
    }

    // epilogue: D[row=(lane>>4)*4+r][col=lane&15] per 16x16 tile; fuse bias.
    // nontemporal: C is written once, never re-read -> keep it out of L3.
    const int qd = lane >> 4;
    const int cl = lane & 15;
#pragma unroll
    for (int j = 0; j < 4; ++j) {
        const int n = bn + wn + j * 16 + cl;
        const float bv = bias[n];
#pragma unroll
        for (int i = 0; i < 4; ++i) {
            const int m0 = bm + wm + i * 16 + qd * 4;
#pragma unroll
            for (int r = 0; r < 4; ++r)
                __builtin_nontemporal_store(acc[i][j][r] + bv,
                                            &C[(size_t)(m0 + r) * OUT_F + n]);
        }
    }
}

// ---------------------------------------------------------------------------
extern "C" void kernel_launch(void* const* d_in, const int* in_sizes, int n_in,
                              void* d_out, int out_size, void* d_ws, size_t ws_size,
                              hipStream_t stream) {
    const float* x    = (const float*)d_in[0];   // [4,2048,4096] fp32
    const int*   qc   = (const int*)d_in[1];     // [4096,4096] int32 codes
    const float* sc   = (const float*)d_in[2];   // [4096,64] fp32
    const float* bias = (const float*)d_in[3];   // [4096]
    const float* lA   = (const float*)d_in[4];   // [16,4096]
    const float* lB   = (const float*)d_in[5];   // [4096,16]
    float* out = (float*)d_out;                  // [4,2048,4096] fp32

    // workspace: x_bf16 (64 MB) + W'_bf16 (32 MB) = 96 MB
    __hip_bfloat16* xb = (__hip_bfloat16*)d_ws;
    __hip_bfloat16* wb = xb + (size_t)M_TOK * IN_F;

    // 16384 cvt blocks + 16384 dequant blocks, interleaved even/odd
    prep_fused<<<32768, 256, 0, stream>>>(x, xb, qc, sc, lA, lB, wb);
    gemm_bt_bias<<<dim3(OUT_F / BN, M_TOK / BM), 256, 0, stream>>>(xb, wb, bias, out);
}